// Round 1
// baseline (6932.616 us; speedup 1.0000x reference)
//
#include <hip/hip_runtime.h>
#include <cstdint>
#include <cstddef>

#define KS 5
#define K3 125

__device__ __forceinline__ unsigned f2ord(float f){
    unsigned u = __float_as_uint(f);
    return (u & 0x80000000u) ? ~u : (u | 0x80000000u);
}
__device__ __forceinline__ float ord2f(unsigned u){
    unsigned b = (u & 0x80000000u) ? (u & 0x7FFFFFFFu) : ~u;
    return __uint_as_float(b);
}

// ---------------- degree histogram ----------------
__global__ void k_deg(const int* __restrict__ dst, int E, int* __restrict__ deg){
    int e = blockIdx.x*blockDim.x + threadIdx.x;
    if(e < E) atomicAdd(&deg[dst[e]], 1);
}

// ---------------- edge scatter into A[dst, kidx, ci] ----------------
__global__ void k_scatter(const int* __restrict__ src, const int* __restrict__ dst,
                          const float* __restrict__ pos, const float* __restrict__ x,
                          int Cin, int ci0, int cc, float inv2r, int E,
                          float* __restrict__ A){
    int t = blockIdx.x*blockDim.x + threadIdx.x;
    if(t >= E*cc) return;
    int e = t / cc;
    int ci = t - e*cc;
    int s = src[e], d = dst[e];
    float fr[3]; int k0[3];
    #pragma unroll
    for(int dim=0; dim<3; dim++){
        float delta = pos[d*3+dim] - pos[s*3+dim];
        float p = delta*inv2r + 0.5f;
        p = fminf(fmaxf(p, 0.f), 1.f);
        float u = p*4.0f;
        float kf = floorf(u); kf = fminf(kf, 3.f);
        fr[dim] = u - kf; k0[dim] = (int)kf;
    }
    float xs = x[(size_t)s*Cin + ci0 + ci];
    size_t base = ((size_t)d*K3)*cc + ci;
    #pragma unroll
    for(int bits=0; bits<8; bits++){
        float w = ((bits&1)? fr[0] : 1.f-fr[0])
                * ((bits&2)? fr[1] : 1.f-fr[1])
                * ((bits&4)? fr[2] : 1.f-fr[2]);
        int kidx = (k0[0]+(bits&1)) + KS*(k0[1]+((bits>>1)&1)) + KS*KS*(k0[2]+((bits>>2)&1));
        atomicAdd(&A[base + (size_t)kidx*cc], w*xs);
    }
}

// ---------------- einsum GEMM: acc[M,Co] += A[M,Kd] * Wmap ----------------
#define TM 128
#define TN 32
#define KB 16
__global__ __launch_bounds__(256) void k_gemm(const float* __restrict__ A,
        const float* __restrict__ W, float* __restrict__ acc,
        int M, int Co, int Kd, int cc, int ci0, int Cin){
    __shared__ __align__(16) float As[KB][TM];
    __shared__ __align__(16) float Bs[KB][TN];
    int tid = threadIdx.x;
    int m0 = blockIdx.x*TM, n0 = blockIdx.y*TN;
    int tm = tid & 31, tn = tid >> 5;
    float r[4][4];
    #pragma unroll
    for(int i=0;i<4;i++)
        #pragma unroll
        for(int j=0;j<4;j++) r[i][j]=0.f;

    for(int k0=0; k0<Kd; k0+=KB){
        #pragma unroll
        for(int l=0;l<8;l++){
            int j = tid + 256*l;
            int m = j >> 4, kr = j & 15;
            int kk = k0 + kr;
            As[kr][m] = (kk < Kd) ? A[(size_t)(m0+m)*Kd + kk] : 0.f;
        }
        #pragma unroll
        for(int l=0;l<2;l++){
            int j = tid + 256*l;
            int kr = j >> 5, n = j & 31;
            int kk = k0 + kr;
            float v = 0.f;
            if(kk < Kd){
                int kW = kk / cc;
                int ciW = kk - kW*cc;
                v = W[(size_t)(kW*Cin + ci0 + ciW)*Co + n0 + n];
            }
            Bs[kr][n] = v;
        }
        __syncthreads();
        #pragma unroll
        for(int kr=0; kr<KB; kr++){
            float4 a4 = *(const float4*)&As[kr][tm*4];
            float4 b4 = *(const float4*)&Bs[kr][tn*4];
            float av[4] = {a4.x, a4.y, a4.z, a4.w};
            float bv[4] = {b4.x, b4.y, b4.z, b4.w};
            #pragma unroll
            for(int i=0;i<4;i++)
                #pragma unroll
                for(int j=0;j<4;j++)
                    r[i][j] += av[i]*bv[j];
        }
        __syncthreads();
    }
    #pragma unroll
    for(int i=0;i<4;i++){
        int m = m0 + tm*4 + i;
        #pragma unroll
        for(int j=0;j<4;j++)
            acc[(size_t)m*Co + n0 + tn*4 + j] += r[i][j];
    }
}

// ---------------- conv epilogue: /deg + x@root + b, ELU, attention col0 ----------------
__global__ void k_finish(const float* __restrict__ acc, const int* __restrict__ deg,
        const float* __restrict__ xin, const float* __restrict__ root,
        const float* __restrict__ bias, const float* __restrict__ Wa,
        const float* __restrict__ ba, float* __restrict__ y,
        float* __restrict__ att, int N, int Cin, int Co){
    extern __shared__ float sm[];
    float* xs  = sm;        // Cin
    float* red = sm + Cin;  // Co
    int n = blockIdx.x, co = threadIdx.x;
    for(int c=co; c<Cin; c+=Co) xs[c] = xin[(size_t)n*Cin + c];
    __syncthreads();
    float v = acc[(size_t)n*Co + co] / (float)max(deg[n], 1);
    float rt = 0.f;
    for(int c=0; c<Cin; c++) rt += xs[c]*root[(size_t)c*Co + co];
    v += rt + bias[co];
    float yv = v > 0.f ? v : expm1f(v);
    y[(size_t)n*Co + co] = yv;
    if(att){
        red[co] = yv * Wa[co*2];
        __syncthreads();
        int cur = Co;
        while(cur > 1){
            int half = (cur+1) >> 1;
            if(co < cur-half) red[co] += red[co+half];
            __syncthreads();
            cur = half;
        }
        if(co==0) att[n] = red[0] + ba[0];
    }
}

// ---------------- pooling ----------------
__global__ void k_pool_init(unsigned* __restrict__ m_u, unsigned* __restrict__ sel,
        float* __restrict__ cntf, float* __restrict__ ppos, int nc){
    int i = blockIdx.x*blockDim.x + threadIdx.x;
    if(i<nc){
        m_u[i]=0u; sel[i]=0xFFFFFFFFu; cntf[i]=0.f;
        ppos[i*3]=0.f; ppos[i*3+1]=0.f; ppos[i*3+2]=0.f;
    }
}
__global__ void k_pool1(const float* __restrict__ att, const int* __restrict__ cl,
        unsigned* __restrict__ m_u, int n){
    int i = blockIdx.x*blockDim.x + threadIdx.x;
    if(i<n) atomicMax(&m_u[cl[i]], f2ord(att[i]));
}
__global__ void k_pool2(const float* __restrict__ att, const int* __restrict__ cl,
        const unsigned* __restrict__ m_u, unsigned* __restrict__ sel,
        float* __restrict__ cntf, float* __restrict__ ppos,
        const float* __restrict__ pos, int n){
    int i = blockIdx.x*blockDim.x + threadIdx.x;
    if(i>=n) return;
    int c = cl[i];
    if(f2ord(att[i]) >= m_u[c]) atomicMin(&sel[c], (unsigned)i);
    atomicAdd(&cntf[c], 1.f);
    atomicAdd(&ppos[c*3+0], pos[i*3+0]);
    atomicAdd(&ppos[c*3+1], pos[i*3+1]);
    atomicAdd(&ppos[c*3+2], pos[i*3+2]);
}
__global__ void k_pool3(const unsigned* __restrict__ sel, const float* __restrict__ cntf,
        const float* __restrict__ ppos, const float* __restrict__ x,
        float* __restrict__ xo, float* __restrict__ poso, int nc, int Co, int nmax){
    int t = blockIdx.x*blockDim.x + threadIdx.x;
    if(t >= nc*Co) return;
    int c = t / Co;
    int co = t - c*Co;
    unsigned s = min(sel[c], (unsigned)(nmax-1));
    xo[(size_t)c*Co + co] = x[(size_t)s*Co + co];
    if(co < 3) poso[c*3+co] = ppos[c*3+co] / fmaxf(cntf[c], 1.f);
}

// ---------------- final voxel max pool ----------------
__global__ void k_vox(const float* __restrict__ x, const float* __restrict__ pos,
        unsigned* __restrict__ mx_u, float* __restrict__ cnt8){
    int nidx = blockIdx.x, ch = threadIdx.x;  // 256 x 256
    int v0 = min(max((int)floorf(pos[nidx*3+0]+0.5f),0),1);
    int v1 = min(max((int)floorf(pos[nidx*3+1]+0.5f),0),1);
    int v2 = min(max((int)floorf(pos[nidx*3+2]+0.5f),0),1);
    int b = nidx >> 3;
    int cl = b*8 + v0*4 + v1*2 + v2;
    atomicMax(&mx_u[cl*256+ch], f2ord(x[nidx*256+ch]));
    if(ch==0) atomicAdd(&cnt8[cl], 1.f);
}

// ---------------- FC + log_softmax ----------------
__global__ __launch_bounds__(256) void k_fc(const unsigned* __restrict__ mx_u,
        const float* __restrict__ cnt8, const float* __restrict__ Wfc,
        const float* __restrict__ bfc, float* __restrict__ out){
    __shared__ float sred[10][256];
    int b = blockIdx.x, tid = threadIdx.x;
    float p[10];
    #pragma unroll
    for(int j=0;j<10;j++) p[j]=0.f;
    for(int idx=tid; idx<2048; idx+=256){
        int v = idx >> 8;
        float val = (cnt8[b*8+v] > 0.f) ? ord2f(mx_u[b*2048+idx]) : 0.f;
        const float* wr = &Wfc[idx*10];
        #pragma unroll
        for(int j=0;j<10;j++) p[j] += val*wr[j];
    }
    #pragma unroll
    for(int j=0;j<10;j++) sred[j][tid]=p[j];
    __syncthreads();
    for(int s=128;s>0;s>>=1){
        if(tid<s){
            #pragma unroll
            for(int j=0;j<10;j++) sred[j][tid]+=sred[j][tid+s];
        }
        __syncthreads();
    }
    if(tid==0){
        float lg[10], mx=-1e30f, se=0.f;
        for(int j=0;j<10;j++){ lg[j]=sred[j][0]+bfc[j]; mx=fmaxf(mx,lg[j]); }
        for(int j=0;j<10;j++) se += expf(lg[j]-mx);
        float lse = mx + logf(se);
        for(int j=0;j<10;j++) out[b*10+j] = lg[j]-lse;
    }
}

extern "C" void kernel_launch(void* const* d_in, const int* in_sizes, int n_in,
                              void* d_out, int out_size, void* d_ws, size_t ws_size,
                              hipStream_t stream){
    const float* x0   = (const float*)d_in[0];
    const float* pos0 = (const float*)d_in[1];
    const float *Wc[5], *rootc[5], *bc[5];
    for(int i=0;i<5;i++){
        Wc[i]    = (const float*)d_in[2+3*i];
        rootc[i] = (const float*)d_in[3+3*i];
        bc[i]    = (const float*)d_in[4+3*i];
    }
    const float *Wa[4], *ba[4];
    for(int i=0;i<4;i++){
        Wa[i] = (const float*)d_in[17+2*i];
        ba[i] = (const float*)d_in[18+2*i];
    }
    const float* Wfc = (const float*)d_in[25];
    const float* bfc = (const float*)d_in[26];
    const int* ei[5]; for(int i=0;i<5;i++) ei[i] = (const int*)d_in[27+i];
    const int* cl[4]; for(int i=0;i<4;i++) cl[i] = (const int*)d_in[32+i];

    const int NPG[5]   = {2048,512,128,32,8};
    const int chans[6] = {1,32,64,96,128,256};
    const float inv2r[5] = {5.f,5.f,4.f,2.f,1.f};
    const int B = 32;

    size_t off = 0;
    auto alloc = [&](size_t bytes)->void*{
        void* p = (char*)d_ws + off;
        off = (off + bytes + 255) & ~(size_t)255;
        return p;
    };
    float*    x_a   = (float*)   alloc((size_t)65536*32*4);
    float*    x_b   = (float*)   alloc((size_t)16384*32*4);
    float*    pos_a = (float*)   alloc((size_t)16384*3*4);
    float*    pos_b = (float*)   alloc((size_t)4096*3*4);
    float*    acc   = (float*)   alloc((size_t)65536*32*4);
    int*      deg   = (int*)     alloc((size_t)65536*4);
    float*    att   = (float*)   alloc((size_t)65536*4);
    unsigned* m_u   = (unsigned*)alloc((size_t)16384*4);
    unsigned* sel   = (unsigned*)alloc((size_t)16384*4);
    float*    cntf  = (float*)   alloc((size_t)16384*4);
    float*    ppos  = (float*)   alloc((size_t)16384*3*4);
    unsigned* mx_u  = (unsigned*)alloc((size_t)256*256*4);
    float*    cnt8  = (float*)   alloc((size_t)256*4);
    float*    A     = (float*)((char*)d_ws + off);
    size_t Abudget  = (ws_size > off) ? (ws_size - off) : 0;

    const float* xin = x0;
    const float* pin = pos0;

    for(int L=0; L<5; L++){
        int N  = B*NPG[L];
        int E  = N*16;
        int Cin = chans[L], Co = chans[L+1];
        const int* srcp = ei[L];
        const int* dstp = ei[L] + E;

        hipMemsetAsync(deg, 0, (size_t)N*4, stream);
        hipMemsetAsync(acc, 0, (size_t)N*Co*4, stream);
        k_deg<<<(E+255)/256, 256, 0, stream>>>(dstp, E, deg);

        size_t rowb = (size_t)N*K3*4;
        int cc = (Abudget >= rowb) ? (int)(Abudget/rowb) : 1;
        if(cc < 1) cc = 1;
        if(cc > Cin) cc = Cin;
        for(int ci0=0; ci0<Cin; ci0+=cc){
            int c = (Cin-ci0 < cc) ? (Cin-ci0) : cc;
            hipMemsetAsync(A, 0, rowb*(size_t)c, stream);
            int tot = E*c;
            k_scatter<<<(tot+255)/256, 256, 0, stream>>>(srcp, dstp, pin, xin,
                                                         Cin, ci0, c, inv2r[L], E, A);
            dim3 g(N/128, Co/32);
            k_gemm<<<g, 256, 0, stream>>>(A, Wc[L], acc, N, Co, K3*c, c, ci0, Cin);
        }

        float* y = x_a;
        k_finish<<<N, Co, (size_t)(Cin+Co)*4, stream>>>(acc, deg, xin, rootc[L], bc[L],
            (L<4)?Wa[L]:nullptr, (L<4)?ba[L]:nullptr, y, (L<4)?att:nullptr, N, Cin, Co);

        if(L<4){
            int nc = B*NPG[L+1];
            float* pout = (L%2==0) ? pos_a : pos_b;
            k_pool_init<<<(nc+255)/256, 256, 0, stream>>>(m_u, sel, cntf, ppos, nc);
            k_pool1<<<(N+255)/256, 256, 0, stream>>>(att, cl[L], m_u, N);
            k_pool2<<<(N+255)/256, 256, 0, stream>>>(att, cl[L], m_u, sel, cntf, ppos, pin, N);
            k_pool3<<<(nc*Co+255)/256, 256, 0, stream>>>(sel, cntf, ppos, y, x_b, pout, nc, Co, N);
            xin = x_b; pin = pout;
        }
    }

    hipMemsetAsync(mx_u, 0, (size_t)256*256*4, stream);
    hipMemsetAsync(cnt8, 0, (size_t)256*4, stream);
    k_vox<<<256, 256, 0, stream>>>(x_a, pin, mx_u, cnt8);
    k_fc<<<32, 256, 0, stream>>>(mx_u, cnt8, Wfc, bfc, (float*)d_out);
}

// Round 2
// 2114.947 us; speedup vs baseline: 3.2779x; 3.2779x over previous
//
#include <hip/hip_runtime.h>
#include <cstdint>
#include <cstddef>

#define KS 5
#define K3 125

__device__ __forceinline__ unsigned f2ord(float f){
    unsigned u = __float_as_uint(f);
    return (u & 0x80000000u) ? ~u : (u | 0x80000000u);
}
__device__ __forceinline__ float ord2f(unsigned u){
    unsigned b = (u & 0x80000000u) ? (u & 0x7FFFFFFFu) : ~u;
    return __uint_as_float(b);
}

// ---------------- degree histogram ----------------
__global__ void k_deg(const int* __restrict__ dst, int E, int* __restrict__ deg){
    int e = blockIdx.x*blockDim.x + threadIdx.x;
    if(e < E) atomicAdd(&deg[dst[e]], 1);
}

// ---------------- edge scatter into A[(dst-n0), kidx*Cin + ci] ----------------
__global__ void k_scatter(const int* __restrict__ src, const int* __restrict__ dst,
                          const float* __restrict__ pos, const float* __restrict__ x,
                          int Cin, int n0, int n1, float inv2r, int E, int Kd,
                          float* __restrict__ A){
    int t = blockIdx.x*blockDim.x + threadIdx.x;
    if(t >= E*Cin) return;
    int e = t / Cin;
    int ci = t - e*Cin;
    int d = dst[e];
    if(d < n0 || d >= n1) return;
    int s = src[e];
    float fr[3]; int k0[3];
    #pragma unroll
    for(int dim=0; dim<3; dim++){
        float delta = pos[d*3+dim] - pos[s*3+dim];
        float p = delta*inv2r + 0.5f;
        p = fminf(fmaxf(p, 0.f), 1.f);
        float u = p*4.0f;
        float kf = floorf(u); kf = fminf(kf, 3.f);
        fr[dim] = u - kf; k0[dim] = (int)kf;
    }
    float xs = x[(size_t)s*Cin + ci];
    size_t base = (size_t)(d-n0)*Kd + ci;
    #pragma unroll
    for(int bits=0; bits<8; bits++){
        float w = ((bits&1)? fr[0] : 1.f-fr[0])
                * ((bits&2)? fr[1] : 1.f-fr[1])
                * ((bits&4)? fr[2] : 1.f-fr[2]);
        int kidx = (k0[0]+(bits&1)) + KS*(k0[1]+((bits>>1)&1)) + KS*KS*(k0[2]+((bits>>2)&1));
        atomicAdd(&A[base + (size_t)kidx*Cin], w*xs);
    }
}

// ---------------- einsum GEMM: acc[n0+m, co] += A[m, kk] * W[kk, co], split-K ----------------
#define TM 128
#define TN 32
#define KB 16
__global__ __launch_bounds__(256) void k_gemm(const float* __restrict__ A,
        const float* __restrict__ W, float* __restrict__ acc,
        int n0, int Co, int Kd, int Kper){
    __shared__ __align__(16) float As[KB][TM];
    __shared__ __align__(16) float Bs[KB][TN];
    int tid = threadIdx.x;
    int m0 = blockIdx.x*TM, n0b = blockIdx.y*TN;
    int kstart = blockIdx.z*Kper;
    int kend = min(Kd, kstart + Kper);
    int tm = tid & 31, tn = tid >> 5;
    float r[4][4];
    #pragma unroll
    for(int i=0;i<4;i++)
        #pragma unroll
        for(int j=0;j<4;j++) r[i][j]=0.f;

    for(int k0=kstart; k0<kend; k0+=KB){
        #pragma unroll
        for(int l=0;l<8;l++){
            int j = tid + 256*l;
            int m = j >> 4, kr = j & 15;
            int kk = k0 + kr;
            As[kr][m] = (kk < kend) ? A[(size_t)(m0+m)*Kd + kk] : 0.f;
        }
        #pragma unroll
        for(int l=0;l<2;l++){
            int j = tid + 256*l;
            int kr = j >> 5, n = j & 31;
            int kk = k0 + kr;
            Bs[kr][n] = (kk < kend) ? W[(size_t)kk*Co + n0b + n] : 0.f;
        }
        __syncthreads();
        #pragma unroll
        for(int kr=0; kr<KB; kr++){
            float4 a4 = *(const float4*)&As[kr][tm*4];
            float4 b4 = *(const float4*)&Bs[kr][tn*4];
            float av[4] = {a4.x, a4.y, a4.z, a4.w};
            float bv[4] = {b4.x, b4.y, b4.z, b4.w};
            #pragma unroll
            for(int i=0;i<4;i++)
                #pragma unroll
                for(int j=0;j<4;j++)
                    r[i][j] += av[i]*bv[j];
        }
        __syncthreads();
    }
    #pragma unroll
    for(int i=0;i<4;i++){
        int m = n0 + m0 + tm*4 + i;
        #pragma unroll
        for(int j=0;j<4;j++)
            atomicAdd(&acc[(size_t)m*Co + n0b + tn*4 + j], r[i][j]);
    }
}

// ---------------- conv epilogue: /deg + x@root + b, ELU, attention col0 ----------------
__global__ void k_finish(const float* __restrict__ acc, const int* __restrict__ deg,
        const float* __restrict__ xin, const float* __restrict__ root,
        const float* __restrict__ bias, const float* __restrict__ Wa,
        const float* __restrict__ ba, float* __restrict__ y,
        float* __restrict__ att, int N, int Cin, int Co){
    extern __shared__ float sm[];
    float* xs  = sm;        // Cin
    float* red = sm + Cin;  // Co
    int n = blockIdx.x, co = threadIdx.x;
    for(int c=co; c<Cin; c+=Co) xs[c] = xin[(size_t)n*Cin + c];
    __syncthreads();
    float v = acc[(size_t)n*Co + co] / (float)max(deg[n], 1);
    float rt = 0.f;
    for(int c=0; c<Cin; c++) rt += xs[c]*root[(size_t)c*Co + co];
    v += rt + bias[co];
    float yv = v > 0.f ? v : expm1f(v);
    y[(size_t)n*Co + co] = yv;
    if(att){
        red[co] = yv * Wa[co*2];
        __syncthreads();
        int cur = Co;
        while(cur > 1){
            int half = (cur+1) >> 1;
            if(co < cur-half) red[co] += red[co+half];
            __syncthreads();
            cur = half;
        }
        if(co==0) att[n] = red[0] + ba[0];
    }
}

// ---------------- pooling ----------------
__global__ void k_pool_init(unsigned* __restrict__ m_u, unsigned* __restrict__ sel,
        float* __restrict__ cntf, float* __restrict__ ppos, int nc){
    int i = blockIdx.x*blockDim.x + threadIdx.x;
    if(i<nc){
        m_u[i]=0u; sel[i]=0xFFFFFFFFu; cntf[i]=0.f;
        ppos[i*3]=0.f; ppos[i*3+1]=0.f; ppos[i*3+2]=0.f;
    }
}
__global__ void k_pool1(const float* __restrict__ att, const int* __restrict__ cl,
        unsigned* __restrict__ m_u, int n){
    int i = blockIdx.x*blockDim.x + threadIdx.x;
    if(i<n) atomicMax(&m_u[cl[i]], f2ord(att[i]));
}
__global__ void k_pool2(const float* __restrict__ att, const int* __restrict__ cl,
        const unsigned* __restrict__ m_u, unsigned* __restrict__ sel,
        float* __restrict__ cntf, float* __restrict__ ppos,
        const float* __restrict__ pos, int n){
    int i = blockIdx.x*blockDim.x + threadIdx.x;
    if(i>=n) return;
    int c = cl[i];
    if(f2ord(att[i]) >= m_u[c]) atomicMin(&sel[c], (unsigned)i);
    atomicAdd(&cntf[c], 1.f);
    atomicAdd(&ppos[c*3+0], pos[i*3+0]);
    atomicAdd(&ppos[c*3+1], pos[i*3+1]);
    atomicAdd(&ppos[c*3+2], pos[i*3+2]);
}
__global__ void k_pool3(const unsigned* __restrict__ sel, const float* __restrict__ cntf,
        const float* __restrict__ ppos, const float* __restrict__ x,
        float* __restrict__ xo, float* __restrict__ poso, int nc, int Co, int nmax){
    int t = blockIdx.x*blockDim.x + threadIdx.x;
    if(t >= nc*Co) return;
    int c = t / Co;
    int co = t - c*Co;
    unsigned s = min(sel[c], (unsigned)(nmax-1));
    xo[(size_t)c*Co + co] = x[(size_t)s*Co + co];
    if(co < 3) poso[c*3+co] = ppos[c*3+co] / fmaxf(cntf[c], 1.f);
}

// ---------------- final voxel max pool ----------------
__global__ void k_vox(const float* __restrict__ x, const float* __restrict__ pos,
        unsigned* __restrict__ mx_u, float* __restrict__ cnt8){
    int nidx = blockIdx.x, ch = threadIdx.x;  // 256 x 256
    int v0 = min(max((int)floorf(pos[nidx*3+0]+0.5f),0),1);
    int v1 = min(max((int)floorf(pos[nidx*3+1]+0.5f),0),1);
    int v2 = min(max((int)floorf(pos[nidx*3+2]+0.5f),0),1);
    int b = nidx >> 3;
    int cl = b*8 + v0*4 + v1*2 + v2;
    atomicMax(&mx_u[cl*256+ch], f2ord(x[nidx*256+ch]));
    if(ch==0) atomicAdd(&cnt8[cl], 1.f);
}

// ---------------- FC + log_softmax ----------------
__global__ __launch_bounds__(256) void k_fc(const unsigned* __restrict__ mx_u,
        const float* __restrict__ cnt8, const float* __restrict__ Wfc,
        const float* __restrict__ bfc, float* __restrict__ out){
    __shared__ float sred[10][256];
    int b = blockIdx.x, tid = threadIdx.x;
    float p[10];
    #pragma unroll
    for(int j=0;j<10;j++) p[j]=0.f;
    for(int idx=tid; idx<2048; idx+=256){
        int v = idx >> 8;
        float val = (cnt8[b*8+v] > 0.f) ? ord2f(mx_u[b*2048+idx]) : 0.f;
        const float* wr = &Wfc[idx*10];
        #pragma unroll
        for(int j=0;j<10;j++) p[j] += val*wr[j];
    }
    #pragma unroll
    for(int j=0;j<10;j++) sred[j][tid]=p[j];
    __syncthreads();
    for(int s=128;s>0;s>>=1){
        if(tid<s){
            #pragma unroll
            for(int j=0;j<10;j++) sred[j][tid]+=sred[j][tid+s];
        }
        __syncthreads();
    }
    if(tid==0){
        float lg[10], mx=-1e30f, se=0.f;
        for(int j=0;j<10;j++){ lg[j]=sred[j][0]+bfc[j]; mx=fmaxf(mx,lg[j]); }
        for(int j=0;j<10;j++) se += expf(lg[j]-mx);
        float lse = mx + logf(se);
        for(int j=0;j<10;j++) out[b*10+j] = lg[j]-lse;
    }
}

extern "C" void kernel_launch(void* const* d_in, const int* in_sizes, int n_in,
                              void* d_out, int out_size, void* d_ws, size_t ws_size,
                              hipStream_t stream){
    const float* x0   = (const float*)d_in[0];
    const float* pos0 = (const float*)d_in[1];
    const float *Wc[5], *rootc[5], *bc[5];
    for(int i=0;i<5;i++){
        Wc[i]    = (const float*)d_in[2+3*i];
        rootc[i] = (const float*)d_in[3+3*i];
        bc[i]    = (const float*)d_in[4+3*i];
    }
    const float *Wa[4], *ba[4];
    for(int i=0;i<4;i++){
        Wa[i] = (const float*)d_in[17+2*i];
        ba[i] = (const float*)d_in[18+2*i];
    }
    const float* Wfc = (const float*)d_in[25];
    const float* bfc = (const float*)d_in[26];
    const int* ei[5]; for(int i=0;i<5;i++) ei[i] = (const int*)d_in[27+i];
    const int* cl[4]; for(int i=0;i<4;i++) cl[i] = (const int*)d_in[32+i];

    const int NPG[5]   = {2048,512,128,32,8};
    const int chans[6] = {1,32,64,96,128,256};
    const float inv2r[5] = {5.f,5.f,4.f,2.f,1.f};
    const int B = 32;

    size_t off = 0;
    auto alloc = [&](size_t bytes)->void*{
        void* p = (char*)d_ws + off;
        off = (off + bytes + 255) & ~(size_t)255;
        return p;
    };
    float*    x_a   = (float*)   alloc((size_t)65536*32*4);
    float*    x_b   = (float*)   alloc((size_t)16384*32*4);
    float*    pos_a = (float*)   alloc((size_t)16384*3*4);
    float*    pos_b = (float*)   alloc((size_t)4096*3*4);
    float*    acc   = (float*)   alloc((size_t)65536*32*4);
    int*      deg   = (int*)     alloc((size_t)65536*4);
    float*    att   = (float*)   alloc((size_t)65536*4);
    unsigned* m_u   = (unsigned*)alloc((size_t)16384*4);
    unsigned* sel   = (unsigned*)alloc((size_t)16384*4);
    float*    cntf  = (float*)   alloc((size_t)16384*4);
    float*    ppos  = (float*)   alloc((size_t)16384*3*4);
    unsigned* mx_u  = (unsigned*)alloc((size_t)256*256*4);
    float*    cnt8  = (float*)   alloc((size_t)256*4);
    float*    A     = (float*)((char*)d_ws + off);
    size_t Abudget  = (ws_size > off) ? (ws_size - off) : 0;

    const float* xin = x0;
    const float* pin = pos0;

    for(int L=0; L<5; L++){
        int N  = B*NPG[L];
        int E  = N*16;
        int Cin = chans[L], Co = chans[L+1];
        int Kd  = K3*Cin;
        const int* srcp = ei[L];
        const int* dstp = ei[L] + E;

        hipMemsetAsync(deg, 0, (size_t)N*4, stream);
        hipMemsetAsync(acc, 0, (size_t)N*Co*4, stream);
        k_deg<<<(E+255)/256, 256, 0, stream>>>(dstp, E, deg);

        // row-chunking: Mc nodes per chunk (multiple of TM), full Cin per chunk
        size_t nodeb = (size_t)Kd*4;
        int Mc = (int)(Abudget / nodeb);
        Mc = (Mc / TM) * TM;
        if(Mc < TM) Mc = TM;          // round-1 evidence: budget >= 33 MB, worst need 8.2 MB
        if(Mc > N) Mc = N;

        for(int rn0=0; rn0<N; rn0+=Mc){
            int rn1 = (rn0+Mc < N) ? rn0+Mc : N;
            int Mr  = rn1 - rn0;      // multiple of TM (N and Mc are)
            hipMemsetAsync(A, 0, (size_t)Mr*Kd*4, stream);
            int tot = E*Cin;
            k_scatter<<<(tot+255)/256, 256, 0, stream>>>(srcp, dstp, pin, xin,
                                                         Cin, rn0, rn1, inv2r[L], E, Kd, A);
            int gx = Mr/TM, gy = Co/TN;
            int S = (768 + gx*gy - 1)/(gx*gy);
            int maxS = (Kd + 127)/128;
            if(S > maxS) S = maxS;
            if(S > 64) S = 64;
            if(S < 1) S = 1;
            int Kper = ((Kd + S - 1)/S + KB - 1)/KB*KB;
            dim3 g(gx, gy, S);
            k_gemm<<<g, 256, 0, stream>>>(A, Wc[L], acc, rn0, Co, Kd, Kper);
        }

        float* y = x_a;
        k_finish<<<N, Co, (size_t)(Cin+Co)*4, stream>>>(acc, deg, xin, rootc[L], bc[L],
            (L<4)?Wa[L]:nullptr, (L<4)?ba[L]:nullptr, y, (L<4)?att:nullptr, N, Cin, Co);

        if(L<4){
            int nc = B*NPG[L+1];
            float* pout = (L%2==0) ? pos_a : pos_b;
            k_pool_init<<<(nc+255)/256, 256, 0, stream>>>(m_u, sel, cntf, ppos, nc);
            k_pool1<<<(N+255)/256, 256, 0, stream>>>(att, cl[L], m_u, N);
            k_pool2<<<(N+255)/256, 256, 0, stream>>>(att, cl[L], m_u, sel, cntf, ppos, pin, N);
            k_pool3<<<(nc*Co+255)/256, 256, 0, stream>>>(sel, cntf, ppos, y, x_b, pout, nc, Co, N);
            xin = x_b; pin = pout;
        }
    }

    hipMemsetAsync(mx_u, 0, (size_t)256*256*4, stream);
    hipMemsetAsync(cnt8, 0, (size_t)256*4, stream);
    k_vox<<<256, 256, 0, stream>>>(x_a, pin, mx_u, cnt8);
    k_fc<<<32, 256, 0, stream>>>(mx_u, cnt8, Wfc, bfc, (float*)d_out);
}